// Round 8
// baseline (251.840 us; speedup 1.0000x reference)
//
#include <hip/hip_runtime.h>
#include <hip/hip_cooperative_groups.h>

namespace cg = cooperative_groups;

// B=2, N=24, E=128, H=8, D=16
#define BB 2
#define NN 24
#define EE 128
#define HH 8
#define DD 16
#define ROWS (BB * NN * NN)   // 1152
#define BJOBS 768             // phase-B jobs: 4 mats x 192 six-row tiles
#define GRID_MAX 1024

// ---------------------------------------------------------------------------
// Fused cooperative kernel; ALL phases grid-stride (correct at any grid size).
// wt: [0]=WlkT [1]=WrkT [2]=WlvT [3]=WrvT [4]=WoutT (16384 floats each).
// launch_bounds(256,4): cap VGPR at 128 -> 4 blocks/CU -> coop grid 1024.
// ---------------------------------------------------------------------------
__global__ __launch_bounds__(256, 4) void fused_kernel(
    const float* __restrict__ query, const float* __restrict__ key_t,
    const float* __restrict__ value,
    const float* __restrict__ W_lk, const float* __restrict__ W_rk,
    const float* __restrict__ W_lv, const float* __restrict__ W_rv,
    const float* __restrict__ W_out,
    float* __restrict__ wt, float* __restrict__ proj,
    float* __restrict__ out)
{
    cg::grid_group grid = cg::this_grid();
    __shared__ float ld[32][33];

    const int t    = threadIdx.x;
    const int nblk = gridDim.x;

    // ---------------- Phase A: weight transposes (80 tile jobs) ------------
    for (int job = blockIdx.x; job < 80; job += nblk) {
        const int mat  = job / 16;
        const int tile = job % 16;
        const int ti = tile >> 2, tj = tile & 3;
        const float* W;
        switch (mat) {
            case 0: W = W_lk; break; case 1: W = W_rk; break;
            case 2: W = W_lv; break; case 3: W = W_rv; break;
            default: W = W_out; break;
        }
        float* WT = wt + mat * 16384;
        #pragma unroll
        for (int e = t; e < 1024; e += 256) {
            const int r = e >> 5, c = e & 31;
            ld[r][c] = W[(ti * 32 + r) * EE + tj * 32 + c];   // coalesced read
        }
        __syncthreads();
        #pragma unroll
        for (int e = t; e < 1024; e += 256) {
            const int c = e >> 5, r = e & 31;
            WT[(tj * 32 + c) * EE + ti * 32 + r] = ld[r][c];  // coalesced write
        }
        __syncthreads();   // protect ld[] before next grid-stride job
    }
    grid.sync();

    // ------- Phase B: projections (768 six-row jobs, 3 rows/thread) --------
    {
        const int j  = t & 127;
        const int rg = t >> 7;
        for (int job = blockIdx.x; job < BJOBS; job += nblk) {
            const int mat  = job / 192;
            const int tile = job % 192;
            const float* X  = (mat == 0) ? query : (mat == 1) ? key_t : value;
            const float* WT = wt + mat * 16384;
            float* Y = proj + (size_t)mat * ROWS * EE;
            const int r0 = tile * 6 + rg * 3;
            const float* xb = X + (size_t)r0 * EE;

            float a0 = 0.f, a1 = 0.f, a2 = 0.f;
            #pragma unroll 4
            for (int kk = 0; kk < 32; ++kk) {
                const float4 x0 = *(const float4*)(xb + kk * 4);
                const float4 x1 = *(const float4*)(xb + EE + kk * 4);
                const float4 x2 = *(const float4*)(xb + 2 * EE + kk * 4);
                const float w0 = WT[(kk * 4 + 0) * EE + j];
                const float w1 = WT[(kk * 4 + 1) * EE + j];
                const float w2 = WT[(kk * 4 + 2) * EE + j];
                const float w3 = WT[(kk * 4 + 3) * EE + j];
                a0 += w0 * x0.x + w1 * x0.y + w2 * x0.z + w3 * x0.w;
                a1 += w0 * x1.x + w1 * x1.y + w2 * x1.z + w3 * x1.w;
                a2 += w0 * x2.x + w1 * x2.y + w2 * x2.z + w3 * x2.w;
            }
            Y[(size_t)r0 * EE + j]       = a0;
            Y[(size_t)(r0 + 1) * EE + j] = a1;
            Y[(size_t)(r0 + 2) * EE + j] = a2;
        }
    }
    grid.sync();

    // ---------------- Phase C: attention + out-projection ------------------
    {
        const int lane = t & 63;
        const int w    = t >> 6;
        const float* lk = proj + 0 * (size_t)ROWS * EE;
        const float* rk = proj + 1 * (size_t)ROWS * EE;
        const float* lv = proj + 2 * (size_t)ROWS * EE;
        const float* rv = proj + 3 * (size_t)ROWS * EE;
        const float* WoutT = wt + 4 * 16384;

        for (int wj0 = blockIdx.x * 4; wj0 < ROWS; wj0 += nblk * 4) {
            const int wj = wj0 + w;            // (b*24 + x)*24 + y
            const int y  = wj % NN;
            const int bx = wj / NN;            // b*24 + x
            const int b  = bx / NN;

            // A: scores (3 per lane; 8-lane groups read contiguous rows)
            float att[3];
            #pragma unroll
            for (int p = 0; p < 3; ++p) {
                const int il = lane + 64 * p;
                const int a  = il >> 3;
                const int h  = il & 7;
                const float4* lp = (const float4*)(lk + ((size_t)(bx * NN + a)) * EE + h * DD);
                const float4* rp = (const float4*)(rk + ((size_t)((b * NN + a) * NN + y)) * EE + h * DD);
                float acc = 0.f;
                #pragma unroll
                for (int c = 0; c < 4; ++c) {
                    const float4 u = lp[c], v = rp[c];
                    acc += u.x * v.x + u.y * v.y + u.z * v.z + u.w * v.w;
                }
                att[p] = acc * 0.25f;          // 1/sqrt(16)
            }

            // B: softmax over a within head groups (lanes with equal l&7)
            float m = fmaxf(att[0], fmaxf(att[1], att[2]));
            m = fmaxf(m, __shfl_xor(m, 8));
            m = fmaxf(m, __shfl_xor(m, 16));
            m = fmaxf(m, __shfl_xor(m, 32));
            float s = 0.f;
            #pragma unroll
            for (int p = 0; p < 3; ++p) { att[p] = __expf(att[p] - m); s += att[p]; }
            s += __shfl_xor(s, 8);
            s += __shfl_xor(s, 16);
            s += __shfl_xor(s, 32);
            const float inv = 1.f / s;
            #pragma unroll
            for (int p = 0; p < 3; ++p) att[p] *= inv;

            // C: weighted outer-product reduction over a (dims 2*lane, +1)
            const int h = lane >> 3;
            float xx = 0.f, xy = 0.f;
            #pragma unroll
            for (int a = 0; a < NN; ++a) {
                const float attv = __shfl(att[a >> 3], ((a & 7) << 3) | h);
                const float2 l2 = *(const float2*)(lv + ((size_t)(bx * NN + a)) * EE + lane * 2);
                const float2 r2 = *(const float2*)(rv + ((size_t)((b * NN + a) * NN + y)) * EE + lane * 2);
                xx += attv * l2.x * r2.x;
                xy += attv * l2.y * r2.y;
            }

            // D: fused out-projection (coalesced WoutT, shfl broadcast x)
            float ox = 0.f, oy = 0.f;
            #pragma unroll 8
            for (int i = 0; i < EE; ++i) {
                const float xv = __shfl((i & 1) ? xy : xx, i >> 1);
                const float2 w2 = *(const float2*)(WoutT + i * EE + lane * 2);
                ox += xv * w2.x;
                oy += xv * w2.y;
            }
            *(float2*)(out + (size_t)wj * EE + lane * 2) = make_float2(ox, oy);
        }
    }
}

// ------------------- fallback path: separate kernels -----------------------
__global__ __launch_bounds__(256) void transpose_kernel(
    const float* __restrict__ W_lk, const float* __restrict__ W_rk,
    const float* __restrict__ W_lv, const float* __restrict__ W_rv,
    const float* __restrict__ W_out, float* __restrict__ wt)
{
    __shared__ float ld[32][33];
    const int blk  = blockIdx.x;
    const int mat  = blk / 16;
    const int tile = blk % 16;
    const int ti = tile >> 2, tj = tile & 3;
    const float* W;
    switch (mat) {
        case 0: W = W_lk; break; case 1: W = W_rk; break;
        case 2: W = W_lv; break; case 3: W = W_rv; break;
        default: W = W_out; break;
    }
    float* WT = wt + mat * 16384;
    const int t = threadIdx.x;
    #pragma unroll
    for (int e = t; e < 1024; e += 256) {
        const int r = e >> 5, c = e & 31;
        ld[r][c] = W[(ti * 32 + r) * EE + tj * 32 + c];
    }
    __syncthreads();
    #pragma unroll
    for (int e = t; e < 1024; e += 256) {
        const int c = e >> 5, r = e & 31;
        WT[(tj * 32 + c) * EE + ti * 32 + r] = ld[r][c];
    }
}

__global__ __launch_bounds__(256) void proj_kernel(
    const float* __restrict__ query, const float* __restrict__ key_t,
    const float* __restrict__ value, const float* __restrict__ wt,
    float* __restrict__ proj)
{
    const int blk  = blockIdx.x;
    const int mat  = blk / 192;
    const int tile = blk % 192;
    const int t  = threadIdx.x;
    const int j  = t & 127;
    const int rg = t >> 7;
    const float* X  = (mat == 0) ? query : (mat == 1) ? key_t : value;
    const float* WT = wt + mat * 16384;
    float* Y = proj + (size_t)mat * ROWS * EE;
    const int r0 = tile * 6 + rg * 3;
    const float* xb = X + (size_t)r0 * EE;

    float a0 = 0.f, a1 = 0.f, a2 = 0.f;
    #pragma unroll 4
    for (int kk = 0; kk < 32; ++kk) {
        const float4 x0 = *(const float4*)(xb + kk * 4);
        const float4 x1 = *(const float4*)(xb + EE + kk * 4);
        const float4 x2 = *(const float4*)(xb + 2 * EE + kk * 4);
        const float w0 = WT[(kk * 4 + 0) * EE + j];
        const float w1 = WT[(kk * 4 + 1) * EE + j];
        const float w2 = WT[(kk * 4 + 2) * EE + j];
        const float w3 = WT[(kk * 4 + 3) * EE + j];
        a0 += w0 * x0.x + w1 * x0.y + w2 * x0.z + w3 * x0.w;
        a1 += w0 * x1.x + w1 * x1.y + w2 * x1.z + w3 * x1.w;
        a2 += w0 * x2.x + w1 * x2.y + w2 * x2.z + w3 * x2.w;
    }
    Y[(size_t)r0 * EE + j]       = a0;
    Y[(size_t)(r0 + 1) * EE + j] = a1;
    Y[(size_t)(r0 + 2) * EE + j] = a2;
}

__global__ __launch_bounds__(64) void attn_kernel(
    const float* __restrict__ proj, const float* __restrict__ wt,
    float* __restrict__ out)
{
    const int lane = threadIdx.x;
    const int wj   = blockIdx.x;
    const int y  = wj % NN;
    const int bx = wj / NN;
    const int b  = bx / NN;

    const float* lk = proj + 0 * (size_t)ROWS * EE;
    const float* rk = proj + 1 * (size_t)ROWS * EE;
    const float* lv = proj + 2 * (size_t)ROWS * EE;
    const float* rv = proj + 3 * (size_t)ROWS * EE;
    const float* WoutT = wt + 4 * 16384;

    float att[3];
    #pragma unroll
    for (int p = 0; p < 3; ++p) {
        const int il = lane + 64 * p;
        const int a  = il >> 3;
        const int h  = il & 7;
        const float4* lp = (const float4*)(lk + ((size_t)(bx * NN + a)) * EE + h * DD);
        const float4* rp = (const float4*)(rk + ((size_t)((b * NN + a) * NN + y)) * EE + h * DD);
        float acc = 0.f;
        #pragma unroll
        for (int c = 0; c < 4; ++c) {
            const float4 u = lp[c], v = rp[c];
            acc += u.x * v.x + u.y * v.y + u.z * v.z + u.w * v.w;
        }
        att[p] = acc * 0.25f;
    }
    float m = fmaxf(att[0], fmaxf(att[1], att[2]));
    m = fmaxf(m, __shfl_xor(m, 8));
    m = fmaxf(m, __shfl_xor(m, 16));
    m = fmaxf(m, __shfl_xor(m, 32));
    float s = 0.f;
    #pragma unroll
    for (int p = 0; p < 3; ++p) { att[p] = __expf(att[p] - m); s += att[p]; }
    s += __shfl_xor(s, 8);
    s += __shfl_xor(s, 16);
    s += __shfl_xor(s, 32);
    const float inv = 1.f / s;
    #pragma unroll
    for (int p = 0; p < 3; ++p) att[p] *= inv;

    const int h = lane >> 3;
    float xx = 0.f, xy = 0.f;
    #pragma unroll
    for (int a = 0; a < NN; ++a) {
        const float attv = __shfl(att[a >> 3], ((a & 7) << 3) | h);
        const float2 l2 = *(const float2*)(lv + ((size_t)(bx * NN + a)) * EE + lane * 2);
        const float2 r2 = *(const float2*)(rv + ((size_t)((b * NN + a) * NN + y)) * EE + lane * 2);
        xx += attv * l2.x * r2.x;
        xy += attv * l2.y * r2.y;
    }
    float ox = 0.f, oy = 0.f;
    #pragma unroll 8
    for (int i = 0; i < EE; ++i) {
        const float xv = __shfl((i & 1) ? xy : xx, i >> 1);
        const float2 w2 = *(const float2*)(WoutT + i * EE + lane * 2);
        ox += xv * w2.x;
        oy += xv * w2.y;
    }
    *(float2*)(out + (size_t)wj * EE + lane * 2) = make_float2(ox, oy);
}

extern "C" void kernel_launch(void* const* d_in, const int* in_sizes, int n_in,
                              void* d_out, int out_size, void* d_ws, size_t ws_size,
                              hipStream_t stream) {
    const float* query = (const float*)d_in[0];
    const float* key_t = (const float*)d_in[1];
    const float* value = (const float*)d_in[2];
    const float* W_lk  = (const float*)d_in[3];
    const float* W_rk  = (const float*)d_in[4];
    const float* W_lv  = (const float*)d_in[5];
    const float* W_rv  = (const float*)d_in[6];
    const float* W_out = (const float*)d_in[7];

    float* wt   = (float*)d_ws;                 // 5 * 16384 floats
    float* proj = wt + 5 * 16384;               // 4 * 1152 * 128 floats
    float* outp = (float*)d_out;

    // Host-side queries only (graph-capture-safe, deterministic every call).
    int coop = 0, ncu = 0, maxPerCU = 0;
    hipDeviceGetAttribute(&coop, hipDeviceAttributeCooperativeLaunch, 0);
    hipDeviceGetAttribute(&ncu, hipDeviceAttributeMultiprocessorCount, 0);
    hipOccupancyMaxActiveBlocksPerMultiprocessor(&maxPerCU, (const void*)fused_kernel, 256, 0);

    const int maxCoop = maxPerCU * ncu;
    if (coop && maxCoop >= 64) {
        const int grid = (maxCoop < GRID_MAX) ? maxCoop : GRID_MAX;
        void* args[] = {
            (void*)&query, (void*)&key_t, (void*)&value,
            (void*)&W_lk, (void*)&W_rk, (void*)&W_lv, (void*)&W_rv, (void*)&W_out,
            (void*)&wt, (void*)&proj, (void*)&outp,
        };
        hipLaunchCooperativeKernel((void*)fused_kernel, dim3(grid), dim3(256),
                                   args, 0, stream);
    } else {
        transpose_kernel<<<80, 256, 0, stream>>>(W_lk, W_rk, W_lv, W_rv, W_out, wt);
        proj_kernel<<<BJOBS, 256, 0, stream>>>(query, key_t, value, wt, proj);
        attn_kernel<<<ROWS, 64, 0, stream>>>(proj, wt, outp);
    }
}

// Round 9
// 138.268 us; speedup vs baseline: 1.8214x; 1.8214x over previous
//
#include <hip/hip_runtime.h>
#include <hip/hip_cooperative_groups.h>

namespace cg = cooperative_groups;

// B=2, N=24, E=128, H=8, D=16
#define BB 2
#define NN 24
#define EE 128
#define HH 8
#define DD 16
#define ROWS (BB * NN * NN)   // 1152
#define PJOBS 768             // 4 mats x 192 six-row tiles (mat = job & 3)
#define GRID_MAX 512
#define WPAD (EE + 1)         // 129: LDS row pad -> (j+k)%32 banks, 2-way free

// ---- stage a 128x128 weight matrix row-major into LDS --------------------
__device__ __forceinline__ void stage_w_lds(float (*Wl)[WPAD],
                                            const float* __restrict__ Wg,
                                            int t)
{
    const float4* Wg4 = (const float4*)Wg;
    #pragma unroll
    for (int e4 = t; e4 < EE * EE / 4; e4 += 256) {   // 16 iters, coalesced
        const int r = e4 >> 5;
        const int c = (e4 & 31) * 4;
        const float4 v = Wg4[e4];
        Wl[r][c]     = v.x;
        Wl[r][c + 1] = v.y;
        Wl[r][c + 2] = v.z;
        Wl[r][c + 3] = v.w;
    }
}

// ---- one 6-row projection tile: Y[r0..r0+2 | rg] = X rows @ W^T ----------
__device__ __forceinline__ void proj_job(const float (*Wl)[WPAD],
                                         const float* __restrict__ X,
                                         float* __restrict__ Y,
                                         int tile, int t)
{
    const int j  = t & 127;
    const int rg = t >> 7;
    const int r0 = tile * 6 + rg * 3;
    const float* xb = X + (size_t)r0 * EE;

    float a0 = 0.f, a1 = 0.f, a2 = 0.f;
    #pragma unroll 8
    for (int k4 = 0; k4 < 32; ++k4) {
        const float4 x0 = *(const float4*)(xb + k4 * 4);
        const float4 x1 = *(const float4*)(xb + EE + k4 * 4);
        const float4 x2 = *(const float4*)(xb + 2 * EE + k4 * 4);
        const float w0 = Wl[j][k4 * 4];
        const float w1 = Wl[j][k4 * 4 + 1];
        const float w2 = Wl[j][k4 * 4 + 2];
        const float w3 = Wl[j][k4 * 4 + 3];
        a0 += w0 * x0.x + w1 * x0.y + w2 * x0.z + w3 * x0.w;
        a1 += w0 * x1.x + w1 * x1.y + w2 * x1.z + w3 * x1.w;
        a2 += w0 * x2.x + w1 * x2.y + w2 * x2.z + w3 * x2.w;
    }
    Y[(size_t)r0 * EE + j]       = a0;
    Y[(size_t)(r0 + 1) * EE + j] = a1;
    Y[(size_t)(r0 + 2) * EE + j] = a2;
}

// ---- one (b,x,y) attention wave-job; Wl holds W_out row-major ------------
__device__ __forceinline__ void attn_job(const float (*Wl)[WPAD],
                                         float* __restrict__ xl,   // xloc[128] LDS, wave-private
                                         const float* __restrict__ proj,
                                         float* __restrict__ out,
                                         int wj, int lane)
{
    const int y  = wj % NN;
    const int bx = wj / NN;            // b*24 + x
    const int b  = bx / NN;

    const float* lk = proj + 0 * (size_t)ROWS * EE;
    const float* rk = proj + 1 * (size_t)ROWS * EE;
    const float* lv = proj + 2 * (size_t)ROWS * EE;
    const float* rv = proj + 3 * (size_t)ROWS * EE;

    // A: scores (3 per lane; 8-lane groups read contiguous rows)
    float att[3];
    #pragma unroll
    for (int p = 0; p < 3; ++p) {
        const int il = lane + 64 * p;
        const int a  = il >> 3;
        const int h  = il & 7;
        const float4* lp = (const float4*)(lk + ((size_t)(bx * NN + a)) * EE + h * DD);
        const float4* rp = (const float4*)(rk + ((size_t)((b * NN + a) * NN + y)) * EE + h * DD);
        float acc = 0.f;
        #pragma unroll
        for (int c = 0; c < 4; ++c) {
            const float4 u = lp[c], v = rp[c];
            acc += u.x * v.x + u.y * v.y + u.z * v.z + u.w * v.w;
        }
        att[p] = acc * 0.25f;          // 1/sqrt(16)
    }

    // B: softmax over a within head groups (lanes with equal l&7)
    float m = fmaxf(att[0], fmaxf(att[1], att[2]));
    m = fmaxf(m, __shfl_xor(m, 8));
    m = fmaxf(m, __shfl_xor(m, 16));
    m = fmaxf(m, __shfl_xor(m, 32));
    float s = 0.f;
    #pragma unroll
    for (int p = 0; p < 3; ++p) { att[p] = __expf(att[p] - m); s += att[p]; }
    s += __shfl_xor(s, 8);
    s += __shfl_xor(s, 16);
    s += __shfl_xor(s, 32);
    const float inv = 1.f / s;
    #pragma unroll
    for (int p = 0; p < 3; ++p) att[p] *= inv;

    // C: weighted outer-product reduction over a (dims 2*lane, 2*lane+1)
    const int h = lane >> 3;
    float xx = 0.f, xy = 0.f;
    #pragma unroll
    for (int a = 0; a < NN; ++a) {
        const float attv = __shfl(att[a >> 3], ((a & 7) << 3) | h);
        const float2 l2 = *(const float2*)(lv + ((size_t)(bx * NN + a)) * EE + lane * 2);
        const float2 r2 = *(const float2*)(rv + ((size_t)((b * NN + a) * NN + y)) * EE + lane * 2);
        xx += attv * l2.x * r2.x;
        xy += attv * l2.y * r2.y;
    }
    xl[2 * lane]     = xx;
    xl[2 * lane + 1] = xy;

    // D: out-projection from LDS; lane computes rows j=lane and j=lane+64.
    // Wl[j][i] banks (j+i)%32 -> 2-way aliasing (free); xl[i] is broadcast.
    float o0 = 0.f, o1 = 0.f;
    #pragma unroll 16
    for (int i = 0; i < EE; ++i) {
        const float xv = xl[i];
        o0 += xv * Wl[lane][i];
        o1 += xv * Wl[lane + 64][i];
    }
    out[(size_t)wj * EE + lane]      = o0;
    out[(size_t)wj * EE + 64 + lane] = o1;
}

// ---------------------------------------------------------------------------
// Fused cooperative kernel (1 grid.sync). Grid must be a multiple of 4 so a
// block's mat (= blk&3) is invariant across phase-1 grid-stride iterations.
// ---------------------------------------------------------------------------
__global__ __launch_bounds__(256) void fused_kernel(
    const float* __restrict__ query, const float* __restrict__ key_t,
    const float* __restrict__ value,
    const float* __restrict__ W_lk, const float* __restrict__ W_rk,
    const float* __restrict__ W_lv, const float* __restrict__ W_rv,
    const float* __restrict__ W_out,
    float* __restrict__ proj, float* __restrict__ out)
{
    cg::grid_group grid = cg::this_grid();
    __shared__ float Wlds[EE][WPAD];     // 66 KB
    __shared__ float xloc[4][EE];        // 2 KB, wave-private slots

    const int t    = threadIdx.x;
    const int blk  = blockIdx.x;
    const int nblk = gridDim.x;

    // ---------------- Phase 1: projections --------------------------------
    {
        const int mat = blk & 3;
        const float* Wg = (mat == 0) ? W_lk : (mat == 1) ? W_rk
                        : (mat == 2) ? W_lv : W_rv;
        const float* X  = (mat == 0) ? query : (mat == 1) ? key_t : value;
        float* Y = proj + (size_t)mat * ROWS * EE;

        stage_w_lds(Wlds, Wg, t);
        __syncthreads();
        for (int job = blk; job < PJOBS; job += nblk)   // job&3 == mat
            proj_job(Wlds, X, Y, job >> 2, t);
    }
    grid.sync();

    // ---------------- Phase 2: attention + out-projection ------------------
    stage_w_lds(Wlds, W_out, t);
    __syncthreads();
    {
        const int lane = t & 63;
        const int w    = t >> 6;
        for (int wgid = w * nblk + blk; wgid < ROWS; wgid += nblk * 4)
            attn_job(Wlds, xloc[w], proj, out, wgid, lane);
    }
}

// ------------------- fallback path: separate kernels -----------------------
__global__ __launch_bounds__(256) void proj_kernel_fb(
    const float* __restrict__ query, const float* __restrict__ key_t,
    const float* __restrict__ value,
    const float* __restrict__ W_lk, const float* __restrict__ W_rk,
    const float* __restrict__ W_lv, const float* __restrict__ W_rv,
    float* __restrict__ proj)
{
    __shared__ float Wlds[EE][WPAD];
    const int t   = threadIdx.x;
    const int job = blockIdx.x;
    const int mat = job & 3;
    const float* Wg = (mat == 0) ? W_lk : (mat == 1) ? W_rk
                    : (mat == 2) ? W_lv : W_rv;
    const float* X  = (mat == 0) ? query : (mat == 1) ? key_t : value;
    float* Y = proj + (size_t)mat * ROWS * EE;

    stage_w_lds(Wlds, Wg, t);
    __syncthreads();
    proj_job(Wlds, X, Y, job >> 2, t);
}

__global__ __launch_bounds__(256) void attn_kernel_fb(
    const float* __restrict__ proj, const float* __restrict__ W_out,
    float* __restrict__ out)
{
    __shared__ float Wlds[EE][WPAD];
    __shared__ float xloc[4][EE];
    const int t = threadIdx.x;

    stage_w_lds(Wlds, W_out, t);
    __syncthreads();
    const int lane = t & 63;
    const int w    = t >> 6;
    const int wj   = blockIdx.x * 4 + w;
    if (wj < ROWS)
        attn_job(Wlds, xloc[w], proj, out, wj, lane);
}

extern "C" void kernel_launch(void* const* d_in, const int* in_sizes, int n_in,
                              void* d_out, int out_size, void* d_ws, size_t ws_size,
                              hipStream_t stream) {
    const float* query = (const float*)d_in[0];
    const float* key_t = (const float*)d_in[1];
    const float* value = (const float*)d_in[2];
    const float* W_lk  = (const float*)d_in[3];
    const float* W_rk  = (const float*)d_in[4];
    const float* W_lv  = (const float*)d_in[5];
    const float* W_rv  = (const float*)d_in[6];
    const float* W_out = (const float*)d_in[7];

    float* proj = (float*)d_ws;                 // 4 * 1152 * 128 floats
    float* outp = (float*)d_out;

    // Host-side queries only (graph-capture-safe, deterministic every call).
    int coop = 0, ncu = 0, maxPerCU = 0;
    hipDeviceGetAttribute(&coop, hipDeviceAttributeCooperativeLaunch, 0);
    hipDeviceGetAttribute(&ncu, hipDeviceAttributeMultiprocessorCount, 0);
    hipOccupancyMaxActiveBlocksPerMultiprocessor(&maxPerCU, (const void*)fused_kernel, 256, 0);

    int grid = maxPerCU * ncu;
    if (grid > GRID_MAX) grid = GRID_MAX;
    grid &= ~3;                                 // multiple of 4 (mat invariant)

    if (coop && grid >= 64) {
        void* args[] = {
            (void*)&query, (void*)&key_t, (void*)&value,
            (void*)&W_lk, (void*)&W_rk, (void*)&W_lv, (void*)&W_rv, (void*)&W_out,
            (void*)&proj, (void*)&outp,
        };
        hipLaunchCooperativeKernel((void*)fused_kernel, dim3(grid), dim3(256),
                                   args, 0, stream);
    } else {
        proj_kernel_fb<<<PJOBS, 256, 0, stream>>>(query, key_t, value,
                                                  W_lk, W_rk, W_lv, W_rv, proj);
        attn_kernel_fb<<<ROWS / 4, 256, 0, stream>>>(proj, W_out, outp);
    }
}